// Round 11
// baseline (484.199 us; speedup 1.0000x reference)
//
#include <hip/hip_runtime.h>
#include <hip/hip_bf16.h>
#include <hip/hip_cooperative_groups.h>

// out[b,t,u,c] = enc[b,t,:]·W[c,:512] + dec[b,u,:]·W[c,512:]
// B=4, T=256, U=64, D=512, C=1024. Output 256 MiB fp32 (write floor ~39us).
//
// Primary: single cooperative kernel (A1 cvt-frag, A2 split-K MFMA GEMMs,
//          B broadcast stream) with grid.sync() between phases.
// Fallback (if hipLaunchCooperativeKernel is refused): R7-proven 3-kernel
//          pipeline at 64.2 us. Launch result checked; both paths identical
//          outputs, deterministic per-environment.

namespace cg = cooperative_groups;

typedef float v4f   __attribute__((ext_vector_type(4)));
typedef float f32x4 __attribute__((ext_vector_type(4)));
typedef __attribute__((ext_vector_type(8))) short short8;

__device__ inline short bf16_of(float f) {
    __hip_bfloat16 h = __float2bfloat16(f);   // RNE
    return *reinterpret_cast<short*>(&h);
}

// ============================ cooperative mega ==============================
__global__ __launch_bounds__(256, 4) void mega(
    const float* __restrict__ enc,   // (1024, 512)
    const float* __restrict__ dec,   // (256, 512)
    const float* __restrict__ W,     // (1024, 1024)
    ushort* __restrict__ Xe_f, ushort* __restrict__ Xd_f,
    ushort* __restrict__ We_f, ushort* __restrict__ Wd_f,
    float* __restrict__ Pe,          // (1024, 1024)
    float* __restrict__ Pd,          // (256, 1024)
    float* __restrict__ out)         // (1024, 64, 1024)
{
    cg::grid_group grid = cg::this_grid();
    const int tid  = threadIdx.x;
    const int w    = tid >> 6;
    const int lane = tid & 63;
    const int l16  = lane & 15;
    const int kq   = lane >> 4;
    const int blk  = blockIdx.x;

    // ---------- A1: cvt + fragment permute ----------
    {
        const int gid = blk * 4 + w;
        if (gid < 3328) {
            const float* src; ushort* dst; int g, rs, co;
            if (gid < 1024)      { src = enc; dst = Xe_f; g = gid;        rs = 512;  co = 0;   }
            else if (gid < 1280) { src = dec; dst = Xd_f; g = gid - 1024; rs = 512;  co = 0;   }
            else if (gid < 2304) { src = W;   dst = We_f; g = gid - 1280; rs = 1024; co = 0;   }
            else                 { src = W;   dst = Wd_f; g = gid - 2304; rs = 1024; co = 512; }
            const int rb = g >> 4, kbi = g & 15;
            const float* p = src + (size_t)(rb * 16 + l16) * rs + co + kbi * 32 + kq * 8;
            float4 lo = *(const float4*)p;
            float4 hi = *(const float4*)(p + 4);
            short8 o;
            o[0] = bf16_of(lo.x); o[1] = bf16_of(lo.y); o[2] = bf16_of(lo.z); o[3] = bf16_of(lo.w);
            o[4] = bf16_of(hi.x); o[5] = bf16_of(hi.y); o[6] = bf16_of(hi.z); o[7] = bf16_of(hi.w);
            *(short8*)&dst[(size_t)g * 512 + lane * 8] = o;
        }
    }
    __threadfence();
    grid.sync();

    // ---------- A2: projection GEMM tiles (split-K, frag loads) ----------
    __shared__ float Ps[16][65];
    for (int task = blk; task < 1280; task += 1024) {
        const ushort *Xf, *Wf; float* P; int mb, cb4;
        if (task < 1024) { Xf = Xe_f; Wf = We_f; P = Pe; mb = task >> 4;          cb4 = task & 15; }
        else             { Xf = Xd_f; Wf = Wd_f; P = Pd; mb = (task - 1024) >> 4; cb4 = (task - 1024) & 15; }

        const int kz  = w >> 1;
        const int wn  = (w & 1) * 32;
        const int cb0 = cb4 * 4 + (w & 1) * 2;

        const short8* xa  = (const short8*)Xf + ((size_t)mb  * 16       + kz * 8) * 64 + lane;
        const short8* wb0 = (const short8*)Wf + ((size_t)cb0 * 16       + kz * 8) * 64 + lane;
        const short8* wb1 = (const short8*)Wf + ((size_t)(cb0 + 1) * 16 + kz * 8) * 64 + lane;

        f32x4 a0 = {0.f,0.f,0.f,0.f}, a1 = {0.f,0.f,0.f,0.f};
#pragma unroll
        for (int s = 0; s < 8; ++s) {
            short8 a  = xa [(size_t)s * 64];
            short8 b0 = wb0[(size_t)s * 64];
            short8 b1 = wb1[(size_t)s * 64];
            a0 = __builtin_amdgcn_mfma_f32_16x16x32_bf16(a, b0, a0, 0, 0, 0);
            a1 = __builtin_amdgcn_mfma_f32_16x16x32_bf16(a, b1, a1, 0, 0, 0);
        }

        if (kz == 1) {
#pragma unroll
            for (int r = 0; r < 4; ++r) {
                Ps[kq * 4 + r][wn + l16]      = a0[r];
                Ps[kq * 4 + r][wn + 16 + l16] = a1[r];
            }
        }
        __syncthreads();
        if (kz == 0) {
            float* p0 = P + (size_t)(mb * 16) * 1024 + cb4 * 64 + wn;
#pragma unroll
            for (int r = 0; r < 4; ++r) {
                const int row = kq * 4 + r;
                p0[(size_t)row * 1024 + l16]      = a0[r] + Ps[row][wn + l16];
                p0[(size_t)row * 1024 + 16 + l16] = a1[r] + Ps[row][wn + 16 + l16];
            }
        }
        __syncthreads();
    }
    __threadfence();
    grid.sync();

    // ---------- B: broadcast-add stream (1 KiB contiguous wave stores) -------
    const int bt = blk;
    const int b  = bt >> 8;
    const int c  = tid << 2;

    const float4 e = *(const float4*)&Pe[(size_t)bt * 1024 + c];
    const float* pd = &Pd[(size_t)b * 64 * 1024 + c];
    float*       po = &out[(size_t)bt * 64 * 1024 + c];

#pragma unroll 8
    for (int u = 0; u < 64; ++u) {
        float4 d = *(const float4*)&pd[(size_t)u * 1024];
        v4f r = {e.x + d.x, e.y + d.y, e.z + d.z, e.w + d.w};
        __builtin_nontemporal_store(r, (v4f*)&po[(size_t)u * 1024]);
    }
}

// ======================= fallback: R7 3-kernel pipeline ======================
__global__ __launch_bounds__(256) void cvt_frag(
    const float* __restrict__ enc, const float* __restrict__ dec,
    const float* __restrict__ W,
    ushort* __restrict__ Xe_f, ushort* __restrict__ Xd_f,
    ushort* __restrict__ We_f, ushort* __restrict__ Wd_f)
{
    const int tid  = threadIdx.x;
    const int lane = tid & 63;
    const int l16  = lane & 15;
    const int kq   = lane >> 4;
    const int gid  = blockIdx.x * 4 + (tid >> 6);

    const float* src; ushort* dst; int g, rs, co;
    if (gid < 1024)      { src = enc; dst = Xe_f; g = gid;        rs = 512;  co = 0;   }
    else if (gid < 1280) { src = dec; dst = Xd_f; g = gid - 1024; rs = 512;  co = 0;   }
    else if (gid < 2304) { src = W;   dst = We_f; g = gid - 1280; rs = 1024; co = 0;   }
    else                 { src = W;   dst = Wd_f; g = gid - 2304; rs = 1024; co = 512; }

    const int rb = g >> 4, kbi = g & 15;
    const float* p = src + (size_t)(rb * 16 + l16) * rs + co + kbi * 32 + kq * 8;
    float4 lo = *(const float4*)p;
    float4 hi = *(const float4*)(p + 4);
    short8 o;
    o[0] = bf16_of(lo.x); o[1] = bf16_of(lo.y); o[2] = bf16_of(lo.z); o[3] = bf16_of(lo.w);
    o[4] = bf16_of(hi.x); o[5] = bf16_of(hi.y); o[6] = bf16_of(hi.z); o[7] = bf16_of(hi.w);
    *(short8*)&dst[(size_t)g * 512 + lane * 8] = o;
}

__global__ __launch_bounds__(256) void dec_gemm_bf16(
    const ushort* __restrict__ Xd_f, const ushort* __restrict__ Wd_f,
    float* __restrict__ Pd)
{
    const int tid  = threadIdx.x;
    const int wave = tid >> 6;
    const int lane = tid & 63;
    const int l16  = lane & 15;
    const int kq   = lane >> 4;

    const int kz = wave >> 1;
    const int wn = (wave & 1) * 32;
    const int mb = blockIdx.y;
    const int cBase = blockIdx.x * 64;
    const int cb0 = blockIdx.x * 4 + (wave & 1) * 2;

    const short8* xa  = (const short8*)Xd_f + (size_t)(mb  * 16 + kz * 8) * 64 + lane;
    const short8* wb0 = (const short8*)Wd_f + (size_t)(cb0       * 16 + kz * 8) * 64 + lane;
    const short8* wb1 = (const short8*)Wd_f + (size_t)((cb0 + 1) * 16 + kz * 8) * 64 + lane;

    f32x4 a0 = {0.f,0.f,0.f,0.f}, a1 = {0.f,0.f,0.f,0.f};
#pragma unroll
    for (int s = 0; s < 8; ++s) {
        short8 a  = xa [(size_t)s * 64];
        short8 b0 = wb0[(size_t)s * 64];
        short8 b1 = wb1[(size_t)s * 64];
        a0 = __builtin_amdgcn_mfma_f32_16x16x32_bf16(a, b0, a0, 0, 0, 0);
        a1 = __builtin_amdgcn_mfma_f32_16x16x32_bf16(a, b1, a1, 0, 0, 0);
    }

    __shared__ float Ps[16][65];
    if (kz == 1) {
#pragma unroll
        for (int r = 0; r < 4; ++r) {
            Ps[kq * 4 + r][wn + l16]      = a0[r];
            Ps[kq * 4 + r][wn + 16 + l16] = a1[r];
        }
    }
    __syncthreads();
    if (kz == 0) {
        float* p0 = Pd + (size_t)(mb * 16) * 1024 + cBase + wn;
#pragma unroll
        for (int r = 0; r < 4; ++r) {
            const int row = kq * 4 + r;
            p0[(size_t)row * 1024 + l16]      = a0[r] + Ps[row][wn + l16];
            p0[(size_t)row * 1024 + 16 + l16] = a1[r] + Ps[row][wn + 16 + l16];
        }
    }
}

__global__ __launch_bounds__(256) void fused_enc_stream(
    const ushort* __restrict__ Xe_f, const ushort* __restrict__ We_f,
    const float* __restrict__ Pd, float* __restrict__ out)
{
    const int tid  = threadIdx.x;
    const int wave = tid >> 6;
    const int lane = tid & 63;
    const int l16  = lane & 15;
    const int kq   = lane >> 4;

    const int kz = wave >> 1;
    const int wn = (wave & 1) * 32;
    const int btBase = blockIdx.y * 16;
    const int cBase  = blockIdx.x * 64;
    const int b      = blockIdx.y >> 4;
    const int cb0    = blockIdx.x * 4 + (wave & 1) * 2;

    __shared__ float encS[2][16][68];
    __shared__ float decS[64][64];

#pragma unroll
    for (int p = 0; p < 4; ++p) {
        int s    = tid + p * 256;
        int row  = s >> 4;
        int slot = s & 15;
        float4 v = *(const float4*)&Pd[(size_t)(b * 64 + row) * 1024 + cBase + slot * 4];
        *(float4*)&decS[row][slot * 4] = v;
    }

    {
        const short8* xa  = (const short8*)Xe_f + (size_t)(blockIdx.y * 16 + kz * 8) * 64 + lane;
        const short8* wb0 = (const short8*)We_f + (size_t)(cb0       * 16 + kz * 8) * 64 + lane;
        const short8* wb1 = (const short8*)We_f + (size_t)((cb0 + 1) * 16 + kz * 8) * 64 + lane;
        f32x4 a0 = {0.f,0.f,0.f,0.f}, a1 = {0.f,0.f,0.f,0.f};
#pragma unroll
        for (int s = 0; s < 8; ++s) {
            short8 a  = xa [(size_t)s * 64];
            short8 b0 = wb0[(size_t)s * 64];
            short8 b1 = wb1[(size_t)s * 64];
            a0 = __builtin_amdgcn_mfma_f32_16x16x32_bf16(a, b0, a0, 0, 0, 0);
            a1 = __builtin_amdgcn_mfma_f32_16x16x32_bf16(a, b1, a1, 0, 0, 0);
        }
#pragma unroll
        for (int r = 0; r < 4; ++r) {
            encS[kz][kq * 4 + r][wn + l16]      = a0[r];
            encS[kz][kq * 4 + r][wn + 16 + l16] = a1[r];
        }
    }

    __syncthreads();

    const int row = tid >> 4;
    const int c4  = (tid & 15) * 4;

    const float4 e0 = *(const float4*)&encS[0][row][c4];
    const float4 e1 = *(const float4*)&encS[1][row][c4];
    const v4f e = {e0.x + e1.x, e0.y + e1.y, e0.z + e1.z, e0.w + e1.w};

    float* po = out + (size_t)(btBase + row) * 64 * 1024 + cBase + c4;

#pragma unroll 8
    for (int u = 0; u < 64; ++u) {
        float4 d = *(const float4*)&decS[u][c4];
        v4f r = {e.x + d.x, e.y + d.y, e.z + d.z, e.w + d.w};
        __builtin_nontemporal_store(r, (v4f*)&po[(size_t)u * 1024]);
    }
}

extern "C" void kernel_launch(void* const* d_in, const int* in_sizes, int n_in,
                              void* d_out, int out_size, void* d_ws, size_t ws_size,
                              hipStream_t stream) {
    const float* enc = (const float*)d_in[0];   // (4,256,512)
    const float* dec = (const float*)d_in[1];   // (4,64,512)
    const float* W   = (const float*)d_in[2];   // (1024,1024)
    float* out = (float*)d_out;

    // Workspace: Pe 4 MiB | Pd 1 MiB | Xe_f 1 MiB | Xd_f 256 KiB |
    //            We_f 1 MiB | Wd_f 1 MiB   (= 8.25 MiB total)
    char* ws = (char*)d_ws;
    float*  Pe   = (float*)(ws);
    float*  Pd   = (float*)(ws + (4u << 20));
    ushort* Xe_f = (ushort*)(ws + (5u << 20));
    ushort* Xd_f = (ushort*)(ws + (6u << 20));
    ushort* We_f = (ushort*)(ws + (6u << 20) + (1u << 18));
    ushort* Wd_f = (ushort*)(ws + (7u << 20) + (1u << 18));

    void* args[] = {(void*)&enc, (void*)&dec, (void*)&W,
                    (void*)&Xe_f, (void*)&Xd_f, (void*)&We_f, (void*)&Wd_f,
                    (void*)&Pe, (void*)&Pd, (void*)&out};
    hipError_t err = hipLaunchCooperativeKernel((const void*)mega,
                                                dim3(1024), dim3(256),
                                                args, 0, stream);
    if (err != hipSuccess) {
        // Deterministic fallback: R7-proven 3-kernel pipeline (64.2 us).
        cvt_frag<<<dim3(832), 256, 0, stream>>>(enc, dec, W, Xe_f, Xd_f, We_f, Wd_f);
        dec_gemm_bf16<<<dim3(16, 16), 256, 0, stream>>>(Xd_f, Wd_f, Pd);
        fused_enc_stream<<<dim3(16, 64), 256, 0, stream>>>(Xe_f, We_f, Pd, out);
    }
}

// Round 12
// 55.987 us; speedup vs baseline: 8.6485x; 8.6485x over previous
//
#include <hip/hip_runtime.h>
#include <hip/hip_bf16.h>

// out[b,t,u,c] = enc[b,t,:]·W[c,:512] + dec[b,u,:]·W[c,512:]
// B=4, T=256, U=64, D=512, C=1024. Output 256 MiB fp32 (write floor ~39us).
//
// R7 structure (best: 64.2us), single change: the output stream uses PLAIN
// cached float4 stores instead of nontemporal. The harness fill kernel hits
// 6.9 GB/ms with cached stores; our NT stream ran ~22% below that. A/B test.
//
// K1 cvt:   fp32 -> bf16 + permute into MFMA-fragment order (1 KB wave-loads).
// K2 dec:   bf16-MFMA dec projection -> Pd (256x1024), fragment loads.
// K3 fused: per block (16 bt x 64 c): Pd chunk -> LDS, enc MFMA tile -> LDS,
//           barrier, stream 256 KiB of output.

typedef float v4f   __attribute__((ext_vector_type(4)));
typedef float f32x4 __attribute__((ext_vector_type(4)));
typedef __attribute__((ext_vector_type(8))) short short8;

__device__ inline short bf16_of(float f) {
    __hip_bfloat16 h = __float2bfloat16(f);   // RNE
    return *reinterpret_cast<short*>(&h);
}

// ---------------- K1: fp32 -> bf16 fragment-layout permute -------------------
// One wave per 16x32 fragment block (1 KiB out). Wave-task ids:
//   [0,1024) enc | [1024,1280) dec | [1280,2304) Wenc | [2304,3328) Wdec
__global__ __launch_bounds__(256) void cvt_frag(
    const float* __restrict__ enc, const float* __restrict__ dec,
    const float* __restrict__ W,
    ushort* __restrict__ Xe_f, ushort* __restrict__ Xd_f,
    ushort* __restrict__ We_f, ushort* __restrict__ Wd_f)
{
    const int tid  = threadIdx.x;
    const int lane = tid & 63;
    const int l16  = lane & 15;
    const int kq   = lane >> 4;
    const int gid  = blockIdx.x * 4 + (tid >> 6);

    const float* src; ushort* dst; int g, rs, co;
    if (gid < 1024)      { src = enc; dst = Xe_f; g = gid;        rs = 512;  co = 0;   }
    else if (gid < 1280) { src = dec; dst = Xd_f; g = gid - 1024; rs = 512;  co = 0;   }
    else if (gid < 2304) { src = W;   dst = We_f; g = gid - 1280; rs = 1024; co = 0;   }
    else                 { src = W;   dst = Wd_f; g = gid - 2304; rs = 1024; co = 512; }

    const int rb = g >> 4, kbi = g & 15;
    const float* p = src + (size_t)(rb * 16 + l16) * rs + co + kbi * 32 + kq * 8;
    float4 lo = *(const float4*)p;
    float4 hi = *(const float4*)(p + 4);
    short8 o;
    o[0] = bf16_of(lo.x); o[1] = bf16_of(lo.y); o[2] = bf16_of(lo.z); o[3] = bf16_of(lo.w);
    o[4] = bf16_of(hi.x); o[5] = bf16_of(hi.y); o[6] = bf16_of(hi.z); o[7] = bf16_of(hi.w);
    *(short8*)&dst[(size_t)g * 512 + lane * 8] = o;
}

// ---------------- K2: dec projection GEMM (fragment loads, split-K) ----------
__global__ __launch_bounds__(256) void dec_gemm_bf16(
    const ushort* __restrict__ Xd_f, const ushort* __restrict__ Wd_f,
    float* __restrict__ Pd)
{
    const int tid  = threadIdx.x;
    const int wave = tid >> 6;
    const int lane = tid & 63;
    const int l16  = lane & 15;
    const int kq   = lane >> 4;

    const int kz = wave >> 1;
    const int wn = (wave & 1) * 32;
    const int mb = blockIdx.y;
    const int cBase = blockIdx.x * 64;
    const int cb0 = blockIdx.x * 4 + (wave & 1) * 2;

    const short8* xa  = (const short8*)Xd_f + (size_t)(mb  * 16 + kz * 8) * 64 + lane;
    const short8* wb0 = (const short8*)Wd_f + (size_t)(cb0       * 16 + kz * 8) * 64 + lane;
    const short8* wb1 = (const short8*)Wd_f + (size_t)((cb0 + 1) * 16 + kz * 8) * 64 + lane;

    f32x4 a0 = {0.f,0.f,0.f,0.f}, a1 = {0.f,0.f,0.f,0.f};
#pragma unroll
    for (int s = 0; s < 8; ++s) {
        short8 a  = xa [(size_t)s * 64];
        short8 b0 = wb0[(size_t)s * 64];
        short8 b1 = wb1[(size_t)s * 64];
        a0 = __builtin_amdgcn_mfma_f32_16x16x32_bf16(a, b0, a0, 0, 0, 0);
        a1 = __builtin_amdgcn_mfma_f32_16x16x32_bf16(a, b1, a1, 0, 0, 0);
    }

    __shared__ float Ps[16][65];
    if (kz == 1) {
#pragma unroll
        for (int r = 0; r < 4; ++r) {
            Ps[kq * 4 + r][wn + l16]      = a0[r];
            Ps[kq * 4 + r][wn + 16 + l16] = a1[r];
        }
    }
    __syncthreads();
    if (kz == 0) {
        float* p0 = Pd + (size_t)(mb * 16) * 1024 + cBase + wn;
#pragma unroll
        for (int r = 0; r < 4; ++r) {
            const int row = kq * 4 + r;
            p0[(size_t)row * 1024 + l16]      = a0[r] + Ps[row][wn + l16];
            p0[(size_t)row * 1024 + 16 + l16] = a1[r] + Ps[row][wn + 16 + l16];
        }
    }
}

// ---------------- K3: fused enc GEMM + broadcast-add stream ------------------
// Grid (16 c-tiles, 64 bt-tiles), 256 threads = 4 waves.
__global__ __launch_bounds__(256) void fused_enc_stream(
    const ushort* __restrict__ Xe_f, const ushort* __restrict__ We_f,
    const float* __restrict__ Pd, float* __restrict__ out)
{
    const int tid  = threadIdx.x;
    const int wave = tid >> 6;
    const int lane = tid & 63;
    const int l16  = lane & 15;
    const int kq   = lane >> 4;

    const int kz = wave >> 1;
    const int wn = (wave & 1) * 32;
    const int btBase = blockIdx.y * 16;
    const int cBase  = blockIdx.x * 64;
    const int b      = blockIdx.y >> 4;
    const int cb0    = blockIdx.x * 4 + (wave & 1) * 2;

    __shared__ float encS[2][16][68];
    __shared__ float decS[64][64];

#pragma unroll
    for (int p = 0; p < 4; ++p) {
        int s    = tid + p * 256;
        int row  = s >> 4;
        int slot = s & 15;
        float4 v = *(const float4*)&Pd[(size_t)(b * 64 + row) * 1024 + cBase + slot * 4];
        *(float4*)&decS[row][slot * 4] = v;
    }

    {
        const short8* xa  = (const short8*)Xe_f + (size_t)(blockIdx.y * 16 + kz * 8) * 64 + lane;
        const short8* wb0 = (const short8*)We_f + (size_t)(cb0       * 16 + kz * 8) * 64 + lane;
        const short8* wb1 = (const short8*)We_f + (size_t)((cb0 + 1) * 16 + kz * 8) * 64 + lane;
        f32x4 a0 = {0.f,0.f,0.f,0.f}, a1 = {0.f,0.f,0.f,0.f};
#pragma unroll
        for (int s = 0; s < 8; ++s) {
            short8 a  = xa [(size_t)s * 64];
            short8 b0 = wb0[(size_t)s * 64];
            short8 b1 = wb1[(size_t)s * 64];
            a0 = __builtin_amdgcn_mfma_f32_16x16x32_bf16(a, b0, a0, 0, 0, 0);
            a1 = __builtin_amdgcn_mfma_f32_16x16x32_bf16(a, b1, a1, 0, 0, 0);
        }
#pragma unroll
        for (int r = 0; r < 4; ++r) {
            encS[kz][kq * 4 + r][wn + l16]      = a0[r];
            encS[kz][kq * 4 + r][wn + 16 + l16] = a1[r];
        }
    }

    __syncthreads();

    const int row = tid >> 4;
    const int c4  = (tid & 15) * 4;

    const float4 e0 = *(const float4*)&encS[0][row][c4];
    const float4 e1 = *(const float4*)&encS[1][row][c4];
    const v4f e = {e0.x + e1.x, e0.y + e1.y, e0.z + e1.z, e0.w + e1.w};

    float* po = out + (size_t)(btBase + row) * 64 * 1024 + cBase + c4;

    // A/B change vs R7: plain cached stores (fill-kernel-style) instead of NT.
#pragma unroll 8
    for (int u = 0; u < 64; ++u) {
        float4 d = *(const float4*)&decS[u][c4];
        v4f r = {e.x + d.x, e.y + d.y, e.z + d.z, e.w + d.w};
        *(v4f*)&po[(size_t)u * 1024] = r;
    }
}

extern "C" void kernel_launch(void* const* d_in, const int* in_sizes, int n_in,
                              void* d_out, int out_size, void* d_ws, size_t ws_size,
                              hipStream_t stream) {
    const float* enc = (const float*)d_in[0];   // (4,256,512)
    const float* dec = (const float*)d_in[1];   // (4,64,512)
    const float* W   = (const float*)d_in[2];   // (1024,1024)
    float* out = (float*)d_out;

    // Workspace: Pd 1 MiB | Xe_f 1 MiB | Xd_f 256 KiB | We_f 1 MiB | Wd_f 1 MiB
    char* ws = (char*)d_ws;
    float*  Pd   = (float*)(ws);
    ushort* Xe_f = (ushort*)(ws + (1u << 20));
    ushort* Xd_f = (ushort*)(ws + (2u << 20));
    ushort* We_f = (ushort*)(ws + (2u << 20) + (1u << 18));
    ushort* Wd_f = (ushort*)(ws + (3u << 20) + (1u << 18));

    cvt_frag<<<dim3(832), 256, 0, stream>>>(enc, dec, W, Xe_f, Xd_f, We_f, Wd_f);
    dec_gemm_bf16<<<dim3(16, 16), 256, 0, stream>>>(Xd_f, Wd_f, Pd);
    fused_enc_stream<<<dim3(16, 64), 256, 0, stream>>>(Xe_f, We_f, Pd, out);
}